// Round 15
// baseline (2479.239 us; speedup 1.0000x reference)
//
#include <hip/hip_runtime.h>
#include <hip/hip_bf16.h>
#include <stdint.h>

#define SEQ   512
#define BATCH 256
#define EMBD  256
#define HID   512
#define OUTD  4

typedef float        f32x4 __attribute__((ext_vector_type(4)));
typedef short        s16x8 __attribute__((ext_vector_type(8)));
typedef unsigned int u32x4 __attribute__((ext_vector_type(4)));
typedef __bf16       bf16x8 __attribute__((ext_vector_type(8)));

static __device__ __forceinline__ short f2bf(float f) {
    union { float f; uint32_t u; } v; v.f = f;
    uint32_t u = v.u;
    u += 0x7fffu + ((u >> 16) & 1u);      // round-to-nearest-even
    return (short)(u >> 16);
}
static __device__ __forceinline__ float bf2f(short s) {
    union { uint32_t u; float f; } v;
    v.u = ((uint32_t)(uint16_t)s) << 16;
    return v.f;
}

static __device__ __forceinline__ f32x4 mfma_bf16(s16x8 a, s16x8 b, f32x4 c) {
    return __builtin_amdgcn_mfma_f32_16x16x32_bf16(
        __builtin_bit_cast(bf16x8, a), __builtin_bit_cast(bf16x8, b), c, 0, 0, 0);
}

// Agent-coherent (L1/L2-bypassing) accesses — validated since round 2.
static __device__ __forceinline__ s16x8 load_coherent_b128(const void* p) {
    s16x8 r;
    asm volatile("global_load_dwordx4 %0, %1, off sc0 sc1"
                 : "=v"(r) : "v"(p) : "memory");
    return r;
}
static __device__ __forceinline__ void store_coherent_b128(void* p, s16x8 v) {
    asm volatile("global_store_dwordx4 %0, %1, off sc0 sc1"
                 :: "v"(p), "v"(v) : "memory");
}
static __device__ __forceinline__ u32x4 load_flags_b128(const unsigned int* p) {
    u32x4 r;
    asm volatile("global_load_dwordx4 %0, %1, off sc0 sc1"
                 : "=v"(r) : "v"(p) : "memory");
    asm volatile("s_waitcnt vmcnt(0)" ::: "memory");
    return r;
}
static __device__ __forceinline__ void store_flag(unsigned int* p, unsigned int v) {
    asm volatile("global_store_dword %0, %1, off sc0 sc1"
                 :: "v"(p), "v"(v) : "memory");
}
static __device__ __forceinline__ void wait_vm0() {
    asm volatile("s_waitcnt vmcnt(0)" ::: "memory");
    __builtin_amdgcn_sched_barrier(0);   // rule #18
}

// Permuted xp index v2: one b128 per consumer thread per step.
// Consumer (bid, t, s) reads xp[((s*64+bid)*256+t)*8 + nt*4 + r] for the
// value at (b = gi*16 + hi*4 + r, c = gj*128 + w*32 + nt*16 + lr), where
// gi=(bid&7)+((bid>>5)<<3), gj=(bid>>3)&3, w=t>>6, hi=(t>>4)&3, lr=t&15.
// Producer inverse (bijective):
static __device__ __forceinline__ size_t xp_pidx2(int s, int b, int c) {
    const int gi  = b >> 4, gj = c >> 7;
    const int bid = (gi & 7) | (gj << 3) | ((gi >> 3) << 5);
    const int hi  = (b >> 2) & 3, r = b & 3;
    const int c7  = c & 127;
    const int w   = c7 >> 5, nt = (c7 >> 4) & 1, lr = c7 & 15;
    const int tt  = w * 64 + hi * 16 + lr;
    return (((size_t)(s * 64 + bid) * 256 + tt) << 3) + nt * 4 + r;
}

// ---------------------------------------------------------------------------
// Kernel 1: xp = emb[text] @ W_ih^T + b_ih + b_hh, bf16, permuted-v2 layout.
// GEMM core byte-identical to the r2/r14-validated kernel.
// ---------------------------------------------------------------------------
__global__ __launch_bounds__(512, 1)
void xproj_kernel(const int* __restrict__ text, const float* __restrict__ emb,
                  const float* __restrict__ W_ih, const float* __restrict__ b_ih,
                  const float* __restrict__ b_hh, short* __restrict__ xp) {
    extern __shared__ char lds[];
    char* As = lds;
    char* Bs = lds + 65536;

    const int t    = threadIdx.x;
    const int row0 = blockIdx.x * 128;
    const int col0 = blockIdx.y * 128;

    {
        const int r   = t >> 2;
        const int kc  = (t & 3) * 64;
        const int tok = text[row0 + r];
        const float* src = emb + (size_t)tok * EMBD + kc;
        #pragma unroll
        for (int u = 0; u < 64; u += 8) {
            f32x4 x0 = *(const f32x4*)(src + u);
            f32x4 x1 = *(const f32x4*)(src + u + 4);
            s16x8 pk;
            pk[0]=f2bf(x0.x); pk[1]=f2bf(x0.y); pk[2]=f2bf(x0.z); pk[3]=f2bf(x0.w);
            pk[4]=f2bf(x1.x); pk[5]=f2bf(x1.y); pk[6]=f2bf(x1.z); pk[7]=f2bf(x1.w);
            int byte = (r * 512 + (kc + u) * 2) ^ ((r & 7) << 4);
            *(s16x8*)(As + byte) = pk;
        }
    }
    {
        const int c  = t >> 2;
        const int kc = (t & 3) * 64;
        const float* src = W_ih + (size_t)(col0 + c) * EMBD + kc;
        #pragma unroll
        for (int u = 0; u < 64; u += 8) {
            f32x4 x0 = *(const f32x4*)(src + u);
            f32x4 x1 = *(const f32x4*)(src + u + 4);
            s16x8 pk;
            pk[0]=f2bf(x0.x); pk[1]=f2bf(x0.y); pk[2]=f2bf(x0.z); pk[3]=f2bf(x0.w);
            pk[4]=f2bf(x1.x); pk[5]=f2bf(x1.y); pk[6]=f2bf(x1.z); pk[7]=f2bf(x1.w);
            int byte = (c * 512 + (kc + u) * 2) ^ ((c & 7) << 4);
            *(s16x8*)(Bs + byte) = pk;
        }
    }
    __syncthreads();

    const int lane = t & 63;
    const int w    = t >> 6;
    const int wm   = w >> 2;
    const int wn   = w & 3;
    const int lr   = lane & 15;
    const int lk   = (lane >> 4) * 8;

    f32x4 acc[4][2] = {};
    #pragma unroll
    for (int kk = 0; kk < 8; ++kk) {
        s16x8 a[4], b[2];
        #pragma unroll
        for (int mt = 0; mt < 4; ++mt) {
            int r = wm * 64 + mt * 16 + lr;
            int byte = (r * 512 + (kk * 32 + lk) * 2) ^ ((r & 7) << 4);
            a[mt] = *(const s16x8*)(As + byte);
        }
        #pragma unroll
        for (int nt = 0; nt < 2; ++nt) {
            int c = wn * 32 + nt * 16 + lr;
            int byte = (c * 512 + (kk * 32 + lk) * 2) ^ ((c & 7) << 4);
            b[nt] = *(const s16x8*)(Bs + byte);
        }
        #pragma unroll
        for (int mt = 0; mt < 4; ++mt)
            #pragma unroll
            for (int nt = 0; nt < 2; ++nt)
                acc[mt][nt] = mfma_bf16(a[mt], b[nt], acc[mt][nt]);
    }

    #pragma unroll
    for (int nt = 0; nt < 2; ++nt) {
        const int c = col0 + wn * 32 + nt * 16 + lr;
        const float bias = b_ih[c] + b_hh[c];
        #pragma unroll
        for (int mt = 0; mt < 4; ++mt) {
            #pragma unroll
            for (int r4 = 0; r4 < 4; ++r4) {
                const int rr = row0 + wm * 64 + mt * 16 + (lane >> 4) * 4 + r4;
                xp[xp_pidx2(rr >> 8, rr & 255, c)] = f2bf(acc[mt][nt][r4] + bias);
            }
        }
    }
}

// ---------------------------------------------------------------------------
// Kernel 2: reliable cross-WG recurrence + FC head (the 12-for-12 class),
// with three latency cuts vs r14:
//   (1) xp consumed as ONE b128/thread/step (permuted-v2), issued pre-poll;
//   (2) ALL threads poll one b128 coherent load of the group's 4 flags
//       (replaces t0-poll + syncthreads — per-thread ordering suffices);
//   (3) per-WG flag = plain coherent store (single writer; previous flag
//       store drained by this step's wait_vm0 before the next is issued,
//       so flags are monotonic; h stores drained before flag issue).
// ---------------------------------------------------------------------------
__global__ __launch_bounds__(256, 1)
void rnn_kernel(const float* __restrict__ W_hh, const short* __restrict__ xp,
                const float* __restrict__ fc_w, const float* __restrict__ fc_b,
                short* __restrict__ hbuf, unsigned int* __restrict__ bar,
                float* __restrict__ out) {
    extern __shared__ char lds[];
    short* hstage = (short*)(lds + 131072);

    const int bid  = blockIdx.x;
    const int gi   = (bid & 7) + ((bid >> 5) << 3);
    const int gj   = (bid >> 3) & 3;
    const int t    = threadIdx.x;
    const int lane = t & 63;
    const int w    = t >> 6;
    const int row0 = gi * 16;
    const int col0 = gj * 128;

    {
        const int c  = t >> 1;
        const int k0 = (t & 1) * 256;
        const float* src = W_hh + (size_t)(col0 + c) * HID + k0;
        #pragma unroll 4
        for (int u = 0; u < 256; u += 8) {
            f32x4 x0 = *(const f32x4*)(src + u);
            f32x4 x1 = *(const f32x4*)(src + u + 4);
            s16x8 pk;
            pk[0]=f2bf(x0.x); pk[1]=f2bf(x0.y); pk[2]=f2bf(x0.z); pk[3]=f2bf(x0.w);
            pk[4]=f2bf(x1.x); pk[5]=f2bf(x1.y); pk[6]=f2bf(x1.z); pk[7]=f2bf(x1.w);
            int byte = (c * 1024 + (k0 + u) * 2) ^ ((c & 7) << 4);
            *(s16x8*)(lds + byte) = pk;
        }
    }
    __syncthreads();

    const int lr    = lane & 15;
    const int lkb   = (lane >> 4) * 16;
    const int arow  = row0 + lr;
    const int crow0 = row0 + (lane >> 4) * 4;
    unsigned int* gflags = bar + gi * 4;       // 16B-aligned group flags

    int p = 0;
    for (int s = 0; s < SEQ; ++s) {
        // xp: one coalesced b128 per thread, issued before the wait
        const s16x8 xv = *(const s16x8*)(
            xp + (((size_t)(s * 64 + bid) * 256 + t) << 3));
        f32x4 acc[2];
        #pragma unroll
        for (int nt = 0; nt < 2; ++nt)
            #pragma unroll
            for (int r = 0; r < 4; ++r)
                acc[nt][r] = bf2f(xv[nt * 4 + r]);

        // wait for previous step's h: ALL threads poll the 4 flag words
        if (s > 0) {
            const unsigned int target = (unsigned int)s;
            int guard = 0;
            for (;;) {
                u32x4 f = load_flags_b128(gflags);
                if (f.x >= target && f.y >= target &&
                    f.z >= target && f.w >= target) break;
                __builtin_amdgcn_s_sleep(1);
                if (++guard > (1 << 22)) break;   // safety valve
            }
        }

        // A-fragments: coherent loads of this lane's h row
        const short* hb   = hbuf + (size_t)p * (BATCH * HID);
        const char*  hrow = (const char*)(hb + (size_t)arow * HID);
        s16x8 areg[16];
        #pragma unroll
        for (int kk = 0; kk < 16; ++kk)
            areg[kk] = load_coherent_b128(hrow + kk * 64 + lkb);
        wait_vm0();

        const int cl0 = w * 32 + lr;
        const int cl1 = cl0 + 16;
        #pragma unroll
        for (int kk = 0; kk < 16; ++kk) {
            const int b0b = (cl0 * 1024 + kk * 64 + lkb) ^ ((cl0 & 7) << 4);
            const int b1b = (cl1 * 1024 + kk * 64 + lkb) ^ ((cl1 & 7) << 4);
            const s16x8 b0v = *(const s16x8*)(lds + b0b);
            const s16x8 b1v = *(const s16x8*)(lds + b1b);
            acc[0] = mfma_bf16(areg[kk], b0v, acc[0]);
            acc[1] = mfma_bf16(areg[kk], b1v, acc[1]);
        }

        // tanh -> LDS transpose stage (row-major [16][128])
        #pragma unroll
        for (int nt = 0; nt < 2; ++nt) {
            const int cl = w * 32 + nt * 16 + lr;
            #pragma unroll
            for (int r = 0; r < 4; ++r)
                hstage[((crow0 - row0) + r) * 128 + cl] = f2bf(tanhf(acc[nt][r]));
        }
        __syncthreads();   // hstage complete (required: transpose cross-thread)

        // vectorized coherent store of this WG's h slice
        {
            const int rr = t >> 4, c8 = (t & 15) * 8;
            s16x8 v = *(const s16x8*)(hstage + rr * 128 + c8);
            short* hn = hbuf + (size_t)(p ^ 1) * (BATCH * HID)
                             + (size_t)(row0 + rr) * HID + (col0 + c8);
            store_coherent_b128(hn, v);
        }
        wait_vm0();        // own h stores (and own prior flag store) at L3
        __syncthreads();   // all threads' stores drained -> flag may publish

        if (t == 0) store_flag(&bar[gi * 4 + gj], (unsigned int)(s + 1));
        p ^= 1;
    }

    // ---- FC head: WGs with gj==0 compute out[rows, 0..3] ----
    if (gj == 0) {
        {
            int guard = 0;
            for (;;) {
                u32x4 f = load_flags_b128(gflags);
                if (f.x >= SEQ && f.y >= SEQ && f.z >= SEQ && f.w >= SEQ) break;
                __builtin_amdgcn_s_sleep(1);
                if (++guard > (1 << 22)) break;
            }
        }

        const int i  = t >> 2;
        const int q  = t & 3;
        const int bl = i >> 2;
        const int o  = i & 3;
        const short* hb = hbuf + (size_t)p * (BATCH * HID)
                               + (size_t)(row0 + bl) * HID + q * 128;
        s16x8 hv[16];
        #pragma unroll
        for (int kk = 0; kk < 16; ++kk)
            hv[kk] = load_coherent_b128((const char*)hb + kk * 16);
        wait_vm0();
        float sum = 0.f;
        #pragma unroll
        for (int kk = 0; kk < 16; ++kk)
            #pragma unroll
            for (int j = 0; j < 8; ++j)
                sum += bf2f(hv[kk][j]) * fc_w[o * HID + q * 128 + kk * 8 + j];
        sum += __shfl_xor(sum, 1);
        sum += __shfl_xor(sum, 2);
        if (q == 0)
            out[(row0 + bl) * OUTD + o] = sum + fc_b[o];
    }
}

// ---------------------------------------------------------------------------
extern "C" void kernel_launch(void* const* d_in, const int* in_sizes, int n_in,
                              void* d_out, int out_size, void* d_ws, size_t ws_size,
                              hipStream_t stream) {
    (void)in_sizes; (void)n_in; (void)out_size;
    const int*   text = (const int*)  d_in[0];
    const float* emb  = (const float*)d_in[1];
    const float* W_ih = (const float*)d_in[2];
    const float* W_hh = (const float*)d_in[3];
    const float* b_ih = (const float*)d_in[4];
    const float* b_hh = (const float*)d_in[5];
    const float* fc_w = (const float*)d_in[6];
    const float* fc_b = (const float*)d_in[7];
    float* out = (float*)d_out;

    char* ws = (char*)d_ws;
    short*        hbuf = (short*)ws;                        // 2*256*512*2 = 512 KB
    unsigned int* bar  = (unsigned int*)(ws + (512 << 10)); // 16 groups x 4 flags
    short*        xpbf = (short*)(ws + (1 << 20));          // permuted-v2 bf16 xp
    const size_t xp_bytes = (size_t)SEQ * BATCH * HID * 2;  // 128 MiB
    const size_t need = ((size_t)1 << 20) + xp_bytes;
    if (ws_size < need) return;

    // zero h0 + flag region (every call: deterministic)
    hipMemsetAsync(ws, 0, (512 << 10) + 4096, stream);

    hipFuncSetAttribute(reinterpret_cast<const void*>(&xproj_kernel),
                        hipFuncAttributeMaxDynamicSharedMemorySize, 131072);
    hipFuncSetAttribute(reinterpret_cast<const void*>(&rnn_kernel),
                        hipFuncAttributeMaxDynamicSharedMemorySize, 135168);
    xproj_kernel<<<dim3(1024, 4, 1), 512, 131072, stream>>>(
        text, emb, W_ih, b_ih, b_hh, xpbf);
    rnn_kernel<<<64, 256, 135168, stream>>>(
        W_hh, xpbf, fc_w, fc_b, hbuf, bar, out);
}